// Round 9
// baseline (267.435 us; speedup 1.0000x reference)
//
#include <hip/hip_runtime.h>
#include <hip/hip_bf16.h>

#define B_   16
#define CIN  256
#define T_   8192
#define D_   64
#define KK   512

typedef __attribute__((ext_vector_type(8)))  short short8v;
typedef __attribute__((ext_vector_type(16))) float f32x16;
typedef unsigned short ushort_t;

__device__ __forceinline__ unsigned f2bf(float f) {          // RTNE float->bf16
    union { float f; unsigned u; } v; v.f = f;
    unsigned r = v.u + 0x7fffu + ((v.u >> 16) & 1u);
    return r >> 16;
}
// HW packed convert: 2 fp32 -> bf16x2 (v_cvt_pk_bf16_f32), RTNE
__device__ __forceinline__ unsigned pk2(float lo, float hi) {
    union { __hip_bfloat162 h; unsigned u; } v;
    v.h = __float22bfloat162_rn(make_float2(lo, hi));
    return v.u;
}

// ---------------------------------------------------------------------------
// Prep: W -> bf16 [64][256], cb -> bf16 [512][64], n2[k] = ||e_k||^2
// ---------------------------------------------------------------------------
__global__ __launch_bounds__(256) void prep_kernel(
    const float* __restrict__ W, const float* __restrict__ cb,
    ushort_t* __restrict__ W16, ushort_t* __restrict__ cb16,
    float* __restrict__ n2)
{
    const int i = blockIdx.x * 256 + threadIdx.x;    // 16384 threads
    W16[i] = (ushort_t)f2bf(W[i]);
    cb16[i]         = (ushort_t)f2bf(cb[i]);
    cb16[i + 16384] = (ushort_t)f2bf(cb[i + 16384]);
    if (i < KK) {
        const float* cr = cb + (size_t)i * 64;
        float s = 0.f;
        #pragma unroll
        for (int d = 0; d < 64; ++d) s = fmaf(cr[d], cr[d], s);
        n2[i] = s;
    }
}

// ---------------------------------------------------------------------------
// Fused main: 512 blocks x 256 thr (4 waves). Block = 256-t slab; wave = 64 t.
//  phase 1 (no barriers): z[t][d] via MFMA 32x32x16; A=W16 from global (L2),
//    B=x from global (coalesced dwords) + v_cvt_pk packs. acc[dt][q] fp32.
//  epilogue: +bias, ||z||^2 (wave-local, shfl), z -> LDS bf16 (swizzled).
//  phase 2: scores via MFMA, B=cb16 from global (L2); rmin fold; shfl min.
// LDS = 36 KB -> 3 blocks/CU (vs 134 KB / 1 block in round 7).
// ---------------------------------------------------------------------------
__global__ __launch_bounds__(256, 3) void fused_kernel(
    const float* __restrict__ x, const ushort_t* __restrict__ W16,
    const float* __restrict__ bias, const ushort_t* __restrict__ cb16,
    const float* __restrict__ n2g, float* __restrict__ out)
{
    __shared__ ushort_t zl[256 * 64];   // [t][d] bf16, slot-swizzled, 32 KB
    __shared__ float n2b[512];
    __shared__ float znb[256];
    __shared__ float bl[64];

    const int tid  = threadIdx.x;
    const int bid  = blockIdx.x;
    const int b    = bid >> 5;
    const int t0   = (bid & 31) << 8;
    const int lane = tid & 63;
    const int l31  = lane & 31;
    const int lh   = lane >> 5;
    const int wid  = tid >> 6;          // 0..3

    n2b[tid]       = n2g[tid];
    n2b[tid + 256] = n2g[tid + 256];
    if (tid < 64) bl[tid] = bias[tid];
    __syncthreads();

    // ---- phase 1: K = 256 c in 16 steps of 16; wave owns t in [twav, twav+64)
    const int twav = wid << 6;
    const ushort_t* wp = W16 + l31 * CIN + lh * 8;                 // +dt*8192 +kk*16
    const float* xB = x + (size_t)(b * CIN + lh * 8) * T_ + t0 + twav + l31;

    f32x16 a00 = (f32x16)(0.f), a01 = (f32x16)(0.f);   // [dt=0][q]
    f32x16 a10 = (f32x16)(0.f), a11 = (f32x16)(0.f);   // [dt=1][q]

    #pragma unroll 2
    for (int kk = 0; kk < 16; ++kk) {
        uint4 w0 = *(const uint4*)(wp + kk * 16);            // d = l31
        uint4 w1 = *(const uint4*)(wp + 8192 + kk * 16);     // d = 32 + l31
        short8v wa0 = __builtin_bit_cast(short8v, w0);
        short8v wa1 = __builtin_bit_cast(short8v, w1);
        const float* xk = xB + (size_t)(kk * 16) * T_;
        #pragma unroll
        for (int q = 0; q < 2; ++q) {
            const float* xp = xk + q * 32;
            float f0 = xp[0];
            float f1 = xp[(size_t)1 * T_];
            float f2 = xp[(size_t)2 * T_];
            float f3 = xp[(size_t)3 * T_];
            float f4 = xp[(size_t)4 * T_];
            float f5 = xp[(size_t)5 * T_];
            float f6 = xp[(size_t)6 * T_];
            float f7 = xp[(size_t)7 * T_];
            uint4 bv;
            bv.x = pk2(f0, f1); bv.y = pk2(f2, f3);
            bv.z = pk2(f4, f5); bv.w = pk2(f6, f7);
            short8v xa = __builtin_bit_cast(short8v, bv);
            if (q == 0) {
                a00 = __builtin_amdgcn_mfma_f32_32x32x16_bf16(wa0, xa, a00, 0, 0, 0);
                a10 = __builtin_amdgcn_mfma_f32_32x32x16_bf16(wa1, xa, a10, 0, 0, 0);
            } else {
                a01 = __builtin_amdgcn_mfma_f32_32x32x16_bf16(wa0, xa, a01, 0, 0, 0);
                a11 = __builtin_amdgcn_mfma_f32_32x32x16_bf16(wa1, xa, a11, 0, 0, 0);
            }
        }
    }

    // ---- epilogue: +bias, ||z||^2, z -> zl (bf16, swizzled 16B slots)
    float zs0 = 0.f, zs1 = 0.f;
#define EPI(A, dt_, q_, zs_) do {                                             \
        const int t_ = twav + (q_) * 32 + l31;                                \
        float ss_ = 0.f;                                                      \
        _Pragma("unroll")                                                     \
        for (int r = 0; r < 16; ++r) {                                        \
            const int d_ = (dt_) * 32 + (r & 3) + 8 * (r >> 2) + 4 * lh;      \
            float v_ = A[r] + bl[d_];                                         \
            A[r] = v_;                                                        \
            ss_ = fmaf(v_, v_, ss_);                                          \
        }                                                                     \
        zs_ += ss_;                                                           \
        _Pragma("unroll")                                                     \
        for (int g = 0; g < 4; ++g) {                                         \
            const int dq_ = (dt_) * 32 + 8 * g + 4 * lh;                      \
            uint2 pk_;                                                        \
            pk_.x = pk2(A[4 * g + 0], A[4 * g + 1]);                          \
            pk_.y = pk2(A[4 * g + 2], A[4 * g + 3]);                          \
            const int s_    = dq_ >> 3;                                       \
            const int half_ = (dq_ >> 2) & 1;                                 \
            *(uint2*)((char*)zl + t_ * 128 + ((s_ ^ (t_ & 7)) << 4)           \
                      + (half_ << 3)) = pk_;                                  \
        }                                                                     \
    } while (0)

    EPI(a00, 0, 0, zs0);
    EPI(a01, 0, 1, zs1);
    EPI(a10, 1, 0, zs0);
    EPI(a11, 1, 1, zs1);
#undef EPI
    zs0 += __shfl_xor(zs0, 32);
    zs1 += __shfl_xor(zs1, 32);
    if (lh == 0) {
        znb[twav + l31]      = zs0;
        znb[twav + 32 + l31] = zs1;
    }
    __syncthreads();

    // ---- phase 2: wave handles t-tiles {2*wid, 2*wid+1}, all 512 k
    #pragma unroll 1
    for (int tl = 0; tl < 2; ++tl) {
        const int tt = wid * 2 + tl;
        const int t  = tt * 32 + l31;
        short8v az[4];
        #pragma unroll
        for (int ks = 0; ks < 4; ++ks) {
            const int s = ks * 2 + lh;
            uint4 v = *(const uint4*)((char*)zl + t * 128 + ((s ^ (t & 7)) << 4));
            az[ks] = __builtin_bit_cast(short8v, v);
        }
        float rmin[16];
        #pragma unroll
        for (int r = 0; r < 16; ++r) rmin[r] = 3.0e38f;

        const ushort_t* cbp = cb16 + l31 * 64 + lh * 8;   // + nt*2048 + ks*16
        #pragma unroll 1
        for (int nt = 0; nt < 16; ++nt) {
            const int n = nt * 32 + l31;
            const float n2v = n2b[n];
            const ushort_t* cq = cbp + nt * 2048;
            uint4 v0 = *(const uint4*)(cq);
            uint4 v1 = *(const uint4*)(cq + 16);
            uint4 v2 = *(const uint4*)(cq + 32);
            uint4 v3 = *(const uint4*)(cq + 48);
            f32x16 acc = (f32x16)(0.f);
            acc = __builtin_amdgcn_mfma_f32_32x32x16_bf16(az[0], __builtin_bit_cast(short8v, v0), acc, 0, 0, 0);
            acc = __builtin_amdgcn_mfma_f32_32x32x16_bf16(az[1], __builtin_bit_cast(short8v, v1), acc, 0, 0, 0);
            acc = __builtin_amdgcn_mfma_f32_32x32x16_bf16(az[2], __builtin_bit_cast(short8v, v2), acc, 0, 0, 0);
            acc = __builtin_amdgcn_mfma_f32_32x32x16_bf16(az[3], __builtin_bit_cast(short8v, v3), acc, 0, 0, 0);
            #pragma unroll
            for (int r = 0; r < 16; ++r)
                rmin[r] = fminf(rmin[r], fmaf(-2.f, acc[r], n2v));
        }
        #pragma unroll
        for (int m = 1; m <= 16; m <<= 1) {
            #pragma unroll
            for (int r = 0; r < 16; ++r)
                rmin[r] = fminf(rmin[r], __shfl_xor(rmin[r], m));
        }
        if (l31 == 0) {
            #pragma unroll
            for (int r = 0; r < 16; ++r) {
                const int tr = tt * 32 + (r & 3) + 8 * (r >> 2) + 4 * lh;
                float v = znb[tr] + rmin[r];
                float2 o; o.x = v; o.y = v;
                *(float2*)(out + (size_t)((bid << 8) + tr) * 2) = o;
            }
        }
    }
}

// ---------------------------------------------------------------------------
extern "C" void kernel_launch(void* const* d_in, const int* in_sizes, int n_in,
                              void* d_out, int out_size, void* d_ws, size_t ws_size,
                              hipStream_t stream) {
    const float* x    = (const float*)d_in[0];
    const float* W    = (const float*)d_in[1];
    const float* bias = (const float*)d_in[2];
    const float* cb   = (const float*)d_in[3];
    float* out = (float*)d_out;

    ushort_t* W16  = (ushort_t*)d_ws;                 // 32 KB
    ushort_t* cb16 = W16 + 16384;                     // 64 KB
    float*    n2   = (float*)(cb16 + 32768);          // 2 KB

    prep_kernel<<<64, 256, 0, stream>>>(W, cb, W16, cb16, n2);
    fused_kernel<<<512, 256, 0, stream>>>(x, W16, bias, cb16, n2, out);
}